// Round 1
// baseline (849.993 us; speedup 1.0000x reference)
//
#include <hip/hip_runtime.h>

#define BN_EPS 1e-3f

__device__ __forceinline__ float gelu_exact(float v) {
    return 0.5f * v * (1.0f + erff(v * 0.70710678118654752440f));
}

// ---------------------------------------------------------------------------
// prep: fold inference BN into transposed dense weights.
// BN(x) = x*s + t, s = g*rsqrt(v+eps), t = b - m*s
// => BN(x)@W + c = x @ (diag(s)W) + (t@W + c)
// Wt[j*K + k] = s[k] * W[k*64 + j]   (transposed for uniform scalar loads)
// cp[j]       = c[j] + sum_k t[k]*W[k*64 + j]
// ---------------------------------------------------------------------------
template <int K>
__device__ void foldK(const float* __restrict__ bn, const float* __restrict__ W,
                      const float* __restrict__ c, float* __restrict__ Wt,
                      float* __restrict__ cp, float* sh_s, float* sh_t) {
    const int t = threadIdx.x;  // blockDim = 128
    if (t < K) {
        float g = bn[t], b = bn[K + t], m = bn[2 * K + t], v = bn[3 * K + t];
        float s = g * rsqrtf(v + BN_EPS);
        sh_s[t] = s;
        sh_t[t] = b - m * s;
    }
    __syncthreads();
    for (int idx = t; idx < K * 64; idx += 128) {
        int j = idx / K, k = idx % K;
        Wt[j * K + k] = sh_s[k] * W[k * 64 + j];
    }
    if (t < 64) {
        float acc = c[t];
        for (int k = 0; k < K; ++k) acc += sh_t[k] * W[k * 64 + t];
        cp[t] = acc;
    }
    __syncthreads();  // before sh_s/sh_t reuse by next fold
}

__global__ void prep_kernel(
    const float* pbn1, const float* pw1, const float* pc1,
    const float* pbn2, const float* pw2, const float* pc2,
    const float* ubn1, const float* uw1, const float* uc1,
    const float* ubn2, const float* uw2, const float* uc2,
    float* W1t, float* c1p, float* W2t, float* c2p,
    float* U1t, float* uc1p, float* U2t, float* uc2p) {
    __shared__ float sh_s[128], sh_t[128];
    foldK<64>(pbn1, pw1, pc1, W1t, c1p, sh_s, sh_t);
    foldK<64>(pbn2, pw2, pc2, W2t, c2p, sh_s, sh_t);
    foldK<128>(ubn1, uw1, uc1, U1t, uc1p, sh_s, sh_t);
    foldK<64>(ubn2, uw2, uc2, U2t, uc2p, sh_s, sh_t);
}

// ---------------------------------------------------------------------------
// ffn: out[r, 0:64] = gelu( concat(A[r,0:KA], B[r,0:KB]) @ Wt^T + cb )
// One thread per row; row held in registers; weight loads are wave-uniform
// (compiler emits s_load from the transposed layout).
// ---------------------------------------------------------------------------
template <int KA, int KB>
__global__ void ffn_kernel(const float* __restrict__ A, const float* __restrict__ B,
                           const float* __restrict__ Wt, const float* __restrict__ cb,
                           float* __restrict__ out, int N) {
    int r = blockIdx.x * 256 + threadIdx.x;
    if (r >= N) return;
    constexpr int K = KA + KB;
    float4 a[KA / 4];
#pragma unroll
    for (int i = 0; i < KA / 4; ++i)
        a[i] = reinterpret_cast<const float4*>(A + (size_t)r * KA)[i];
    float4 b[(KB > 0 ? KB : 4) / 4];
    if (KB > 0) {
#pragma unroll
        for (int i = 0; i < KB / 4; ++i)
            b[i] = reinterpret_cast<const float4*>(B + (size_t)r * KB)[i];
    }
    for (int j4 = 0; j4 < 16; ++j4) {
        float4 og;
#pragma unroll
        for (int jj = 0; jj < 4; ++jj) {
            const int j = j4 * 4 + jj;
            const float4* w = reinterpret_cast<const float4*>(Wt + (size_t)j * K);
            float acc0 = 0.f, acc1 = 0.f;
#pragma unroll
            for (int i = 0; i < KA / 4; ++i) {
                float4 w4 = w[i];
                acc0 += a[i].x * w4.x + a[i].y * w4.y;
                acc1 += a[i].z * w4.z + a[i].w * w4.w;
            }
            if (KB > 0) {
#pragma unroll
                for (int i = 0; i < KB / 4; ++i) {
                    float4 w4 = w[KA / 4 + i];
                    acc0 += b[i].x * w4.x + b[i].y * w4.y;
                    acc1 += b[i].z * w4.z + b[i].w * w4.w;
                }
            }
            (&og.x)[jj] = gelu_exact(acc0 + acc1 + cb[j]);
        }
        reinterpret_cast<float4*>(out + (size_t)r * 64)[j4] = og;
    }
}

// ---------------------------------------------------------------------------
// CSR build: histogram -> exclusive scan -> scatter
// ---------------------------------------------------------------------------
__global__ void hist_kernel(const int* __restrict__ node_idx, int* __restrict__ deg, int E) {
    int e = blockIdx.x * 256 + threadIdx.x;
    if (e < E) atomicAdd(&deg[node_idx[e]], 1);
}

__global__ void scan_kernel(const int* __restrict__ deg, int* __restrict__ offs, int N) {
    __shared__ int wsum[16];
    __shared__ int carry_sh;
    const int tid = threadIdx.x, lane = tid & 63, wv = tid >> 6;  // blockDim = 1024
    if (tid == 0) carry_sh = 0;
    __syncthreads();
    for (int base = 0; base < N; base += 1024) {
        int i = base + tid;
        int v = (i < N) ? deg[i] : 0;
        int inc = v;
#pragma unroll
        for (int d = 1; d < 64; d <<= 1) {
            int n = __shfl_up(inc, (unsigned)d, 64);
            if (lane >= d) inc += n;
        }
        if (lane == 63) wsum[wv] = inc;
        __syncthreads();
        if (wv == 0) {
            int s = (lane < 16) ? wsum[lane] : 0;
#pragma unroll
            for (int d = 1; d < 16; d <<= 1) {
                int n = __shfl_up(s, (unsigned)d, 64);
                if (lane >= d) s += n;
            }
            if (lane < 16) wsum[lane] = s;
        }
        __syncthreads();
        int carry = carry_sh;
        int waveoff = wv ? wsum[wv - 1] : 0;
        if (i < N) offs[i] = carry + waveoff + inc - v;
        int total = carry + wsum[15];
        __syncthreads();
        if (tid == 0) carry_sh = total;
        __syncthreads();
    }
    if (threadIdx.x == 0) offs[N] = carry_sh;
}

__global__ void copy_kernel(const int* __restrict__ src, int* __restrict__ dst, int N) {
    int i = blockIdx.x * 256 + threadIdx.x;
    if (i < N) dst[i] = src[i];
}

__global__ void scatter_kernel(const int* __restrict__ node_idx, const int* __restrict__ nbr_idx,
                               const float* __restrict__ ew, int* __restrict__ cursor,
                               int* __restrict__ nbr_s, float* __restrict__ ew_s, int E) {
    int e = blockIdx.x * 256 + threadIdx.x;
    if (e < E) {
        int p = atomicAdd(&cursor[node_idx[e]], 1);
        nbr_s[p] = nbr_idx[e];
        ew_s[p] = ew[e];
    }
}

// ---------------------------------------------------------------------------
// aggregation: wave per node, lane = feature dim. Coalesced 256B row reads,
// no float atomics. mean = sum / max(deg,1).
// ---------------------------------------------------------------------------
__global__ void agg_kernel(const float* __restrict__ y, const int* __restrict__ offs,
                           const int* __restrict__ nbr_s, const float* __restrict__ ew_s,
                           float* __restrict__ agg, int N) {
    int gw = (blockIdx.x * 256 + threadIdx.x) >> 6;
    int lane = threadIdx.x & 63;
    if (gw >= N) return;
    int s0 = offs[gw], s1 = offs[gw + 1];
    float acc = 0.f;
    for (int i = s0; i < s1; ++i) {
        int nbr = nbr_s[i];
        float w = ew_s[i];
        acc += w * y[(size_t)nbr * 64 + lane];
    }
    float cnt = (float)(s1 - s0);
    agg[(size_t)gw * 64 + lane] = acc / fmaxf(cnt, 1.0f);
}

// ---------------------------------------------------------------------------
extern "C" void kernel_launch(void* const* d_in, const int* in_sizes, int n_in,
                              void* d_out, int out_size, void* d_ws, size_t ws_size,
                              hipStream_t stream) {
    const float* x    = (const float*)d_in[0];
    const int*   edges= (const int*)d_in[1];
    const float* ew   = (const float*)d_in[2];
    const float* pbn1 = (const float*)d_in[3];
    const float* pw1  = (const float*)d_in[4];
    const float* pc1  = (const float*)d_in[5];
    const float* pbn2 = (const float*)d_in[6];
    const float* pw2  = (const float*)d_in[7];
    const float* pc2  = (const float*)d_in[8];
    const float* ubn1 = (const float*)d_in[9];
    const float* uw1  = (const float*)d_in[10];
    const float* uc1  = (const float*)d_in[11];
    const float* ubn2 = (const float*)d_in[12];
    const float* uw2  = (const float*)d_in[13];
    const float* uc2  = (const float*)d_in[14];
    float* out = (float*)d_out;

    const int N = in_sizes[0] / 64;
    const int E = in_sizes[2];
    const int* node_idx = edges;
    const int* nbr_idx  = edges + E;

    // workspace carve-up (256B aligned); total ~40 MB
    char* p = (char*)d_ws;
    auto alloc = [&](size_t bytes) {
        char* q = p;
        p += (bytes + 255) & ~(size_t)255;
        return q;
    };
    float* h1    = (float*)alloc((size_t)N * 64 * 4);  // intermediate / agg buffer
    float* W1t   = (float*)alloc(64 * 64 * 4);
    float* c1p   = (float*)alloc(64 * 4);
    float* W2t   = (float*)alloc(64 * 64 * 4);
    float* c2p   = (float*)alloc(64 * 4);
    float* U1t   = (float*)alloc(128 * 64 * 4);
    float* uc1p  = (float*)alloc(64 * 4);
    float* U2t   = (float*)alloc(64 * 64 * 4);
    float* uc2p  = (float*)alloc(64 * 4);
    float* ew_s  = (float*)alloc((size_t)E * 4);
    int*   nbr_s = (int*)alloc((size_t)E * 4);
    int*   deg   = (int*)alloc((size_t)N * 4);
    int*   offs  = (int*)alloc((size_t)(N + 1) * 4);
    int*   cur   = (int*)alloc((size_t)N * 4);

    float* yb = out;  // d_out doubles as the y / post-u1 intermediate (row-local RW, safe)

    hipMemsetAsync(deg, 0, (size_t)N * 4, stream);
    prep_kernel<<<1, 128, 0, stream>>>(pbn1, pw1, pc1, pbn2, pw2, pc2,
                                       ubn1, uw1, uc1, ubn2, uw2, uc2,
                                       W1t, c1p, W2t, c2p, U1t, uc1p, U2t, uc2p);
    hist_kernel<<<(E + 255) / 256, 256, 0, stream>>>(node_idx, deg, E);
    scan_kernel<<<1, 1024, 0, stream>>>(deg, offs, N);
    copy_kernel<<<(N + 255) / 256, 256, 0, stream>>>(offs, cur, N);
    scatter_kernel<<<(E + 255) / 256, 256, 0, stream>>>(node_idx, nbr_idx, ew, cur,
                                                        nbr_s, ew_s, E);
    // node-level FFN: y = FFN2(FFN1(x))   (computed per node, not per edge!)
    ffn_kernel<64, 0><<<(N + 255) / 256, 256, 0, stream>>>(x, nullptr, W1t, c1p, h1, N);
    ffn_kernel<64, 0><<<(N + 255) / 256, 256, 0, stream>>>(h1, nullptr, W2t, c2p, yb, N);
    // segment mean of y[nbr]*ew over node_idx
    agg_kernel<<<(N + 3) / 4, 256, 0, stream>>>(yb, offs, nbr_s, ew_s, h1, N);
    // update FFN on concat(x, agg)
    ffn_kernel<64, 64><<<(N + 255) / 256, 256, 0, stream>>>(x, h1, U1t, uc1p, yb, N);
    ffn_kernel<64, 0><<<(N + 255) / 256, 256, 0, stream>>>(yb, nullptr, U2t, uc2p, out, N);
}

// Round 2
// 837.074 us; speedup vs baseline: 1.0154x; 1.0154x over previous
//
#include <hip/hip_runtime.h>

#define BN_EPS 1e-3f

__device__ __forceinline__ float gelu_exact(float v) {
    return 0.5f * v * (1.0f + erff(v * 0.70710678118654752440f));
}

// ---------------------------------------------------------------------------
// prep: fold inference BN into transposed dense weights.
// BN(x) = x*s + t, s = g*rsqrt(v+eps), t = b - m*s
// => BN(x)@W + c = x @ (diag(s)W) + (t@W + c)
// Wt[j*K + k] = s[k] * W[k*64 + j]   (transposed for uniform scalar loads)
// cp[j]       = c[j] + sum_k t[k]*W[k*64 + j]
// ---------------------------------------------------------------------------
template <int K>
__device__ void foldK(const float* __restrict__ bn, const float* __restrict__ W,
                      const float* __restrict__ c, float* __restrict__ Wt,
                      float* __restrict__ cp, float* sh_s, float* sh_t) {
    const int t = threadIdx.x;  // blockDim = 128
    if (t < K) {
        float g = bn[t], b = bn[K + t], m = bn[2 * K + t], v = bn[3 * K + t];
        float s = g * rsqrtf(v + BN_EPS);
        sh_s[t] = s;
        sh_t[t] = b - m * s;
    }
    __syncthreads();
    for (int idx = t; idx < K * 64; idx += 128) {
        int j = idx / K, k = idx % K;
        Wt[j * K + k] = sh_s[k] * W[k * 64 + j];
    }
    if (t < 64) {
        float acc = c[t];
        for (int k = 0; k < K; ++k) acc += sh_t[k] * W[k * 64 + t];
        cp[t] = acc;
    }
    __syncthreads();  // before sh_s/sh_t reuse by next fold
}

__global__ void prep_kernel(
    const float* pbn1, const float* pw1, const float* pc1,
    const float* pbn2, const float* pw2, const float* pc2,
    const float* ubn1, const float* uw1, const float* uc1,
    const float* ubn2, const float* uw2, const float* uc2,
    float* W1t, float* c1p, float* W2t, float* c2p,
    float* U1t, float* uc1p, float* U2t, float* uc2p) {
    __shared__ float sh_s[128], sh_t[128];
    foldK<64>(pbn1, pw1, pc1, W1t, c1p, sh_s, sh_t);
    foldK<64>(pbn2, pw2, pc2, W2t, c2p, sh_s, sh_t);
    foldK<128>(ubn1, uw1, uc1, U1t, uc1p, sh_s, sh_t);
    foldK<64>(ubn2, uw2, uc2, U2t, uc2p, sh_s, sh_t);
}

// ---------------------------------------------------------------------------
// Fused 2-layer FFN: out = gelu(gelu(rowK1 @ W1 + c1) @ W2 + c2)
// rowK1 = A0[row,0:64]  (++ A1[row,0:64] when K1==128)
// Block = 256 thr = 4 waves, handles 64 rows. Wave w owns output cols
// [16w,16w+16); lane = row. Weight loads are wave-uniform (scalar pipe).
// Inter-layer exchange through a 17 KB LDS H tile.
// ---------------------------------------------------------------------------
template <int K1>
__global__ void __launch_bounds__(256, 4) ffn2_fused(
    const float* __restrict__ A0, const float* __restrict__ A1,
    const float* __restrict__ W1t, const float* __restrict__ c1,
    const float* __restrict__ W2t, const float* __restrict__ c2,
    float* __restrict__ out, int N) {
    __shared__ float H[64][68];  // +4 pad: 8-way instead of 32-way on reads
    const int lane = threadIdx.x & 63;
    const int wv = __builtin_amdgcn_readfirstlane(threadIdx.x >> 6);
    const int jb = wv * 16;
    const int row = blockIdx.x * 64 + lane;

    float acc[16];
#pragma unroll
    for (int jj = 0; jj < 16; ++jj) acc[jj] = c1[jb + jj];

    if (row < N) {
        const float4* a0 = reinterpret_cast<const float4*>(A0 + (size_t)row * 64);
#pragma unroll 4
        for (int kc = 0; kc < 16; ++kc) {
            float4 a4 = a0[kc];
#pragma unroll
            for (int jj = 0; jj < 16; ++jj) {
                float4 w4 = *reinterpret_cast<const float4*>(
                    W1t + (size_t)(jb + jj) * K1 + kc * 4);
                acc[jj] += a4.x * w4.x + a4.y * w4.y + a4.z * w4.z + a4.w * w4.w;
            }
        }
        if (K1 == 128) {
            const float4* a1 = reinterpret_cast<const float4*>(A1 + (size_t)row * 64);
#pragma unroll 4
            for (int kc = 0; kc < 16; ++kc) {
                float4 a4 = a1[kc];
#pragma unroll
                for (int jj = 0; jj < 16; ++jj) {
                    float4 w4 = *reinterpret_cast<const float4*>(
                        W1t + (size_t)(jb + jj) * K1 + 64 + kc * 4);
                    acc[jj] += a4.x * w4.x + a4.y * w4.y + a4.z * w4.z + a4.w * w4.w;
                }
            }
        }
    }
    // gelu + publish h slice to LDS (unconditional: garbage rows never stored)
#pragma unroll
    for (int q = 0; q < 4; ++q) {
        float4 h4;
#pragma unroll
        for (int jj = 0; jj < 4; ++jj) (&h4.x)[jj] = gelu_exact(acc[q * 4 + jj]);
        *reinterpret_cast<float4*>(&H[lane][jb + q * 4]) = h4;
    }
    __syncthreads();

    float acc2[16];
#pragma unroll
    for (int jj = 0; jj < 16; ++jj) acc2[jj] = c2[jb + jj];
#pragma unroll 4
    for (int kc = 0; kc < 16; ++kc) {
        float4 h4 = *reinterpret_cast<const float4*>(&H[lane][kc * 4]);
#pragma unroll
        for (int jj = 0; jj < 16; ++jj) {
            float4 w4 = *reinterpret_cast<const float4*>(
                W2t + (size_t)(jb + jj) * 64 + kc * 4);
            acc2[jj] += h4.x * w4.x + h4.y * w4.y + h4.z * w4.z + h4.w * w4.w;
        }
    }
    if (row < N) {
#pragma unroll
        for (int q = 0; q < 4; ++q) {
            float4 o4;
#pragma unroll
            for (int jj = 0; jj < 4; ++jj) (&o4.x)[jj] = gelu_exact(acc2[q * 4 + jj]);
            *reinterpret_cast<float4*>(out + (size_t)row * 64 + jb + q * 4) = o4;
        }
    }
}

// ---------------------------------------------------------------------------
// CSR build: histogram -> exclusive scan -> scatter
// ---------------------------------------------------------------------------
__global__ void hist_kernel(const int* __restrict__ node_idx, int* __restrict__ deg, int E) {
    int e = blockIdx.x * 256 + threadIdx.x;
    if (e < E) atomicAdd(&deg[node_idx[e]], 1);
}

__global__ void scan_kernel(const int* __restrict__ deg, int* __restrict__ offs, int N) {
    __shared__ int wsum[16];
    __shared__ int carry_sh;
    const int tid = threadIdx.x, lane = tid & 63, wv = tid >> 6;  // blockDim = 1024
    if (tid == 0) carry_sh = 0;
    __syncthreads();
    for (int base = 0; base < N; base += 1024) {
        int i = base + tid;
        int v = (i < N) ? deg[i] : 0;
        int inc = v;
#pragma unroll
        for (int d = 1; d < 64; d <<= 1) {
            int n = __shfl_up(inc, (unsigned)d, 64);
            if (lane >= d) inc += n;
        }
        if (lane == 63) wsum[wv] = inc;
        __syncthreads();
        if (wv == 0) {
            int s = (lane < 16) ? wsum[lane] : 0;
#pragma unroll
            for (int d = 1; d < 16; d <<= 1) {
                int n = __shfl_up(s, (unsigned)d, 64);
                if (lane >= d) s += n;
            }
            if (lane < 16) wsum[lane] = s;
        }
        __syncthreads();
        int carry = carry_sh;
        int waveoff = wv ? wsum[wv - 1] : 0;
        if (i < N) offs[i] = carry + waveoff + inc - v;
        int total = carry + wsum[15];
        __syncthreads();
        if (tid == 0) carry_sh = total;
        __syncthreads();
    }
    if (threadIdx.x == 0) offs[N] = carry_sh;
}

__global__ void copy_kernel(const int* __restrict__ src, int* __restrict__ dst, int N) {
    int i = blockIdx.x * 256 + threadIdx.x;
    if (i < N) dst[i] = src[i];
}

__global__ void scatter_kernel(const int* __restrict__ node_idx, const int* __restrict__ nbr_idx,
                               const float* __restrict__ ew, int* __restrict__ cursor,
                               int* __restrict__ nbr_s, float* __restrict__ ew_s, int E) {
    int e = blockIdx.x * 256 + threadIdx.x;
    if (e < E) {
        int p = atomicAdd(&cursor[node_idx[e]], 1);
        nbr_s[p] = nbr_idx[e];
        ew_s[p] = ew[e];
    }
}

// ---------------------------------------------------------------------------
// aggregation: wave per node, lane = feature dim. Coalesced 256B row reads,
// no float atomics. mean = sum / max(deg,1).
// ---------------------------------------------------------------------------
__global__ void agg_kernel(const float* __restrict__ y, const int* __restrict__ offs,
                           const int* __restrict__ nbr_s, const float* __restrict__ ew_s,
                           float* __restrict__ agg, int N) {
    int gw = (blockIdx.x * 256 + threadIdx.x) >> 6;
    int lane = threadIdx.x & 63;
    if (gw >= N) return;
    int s0 = offs[gw], s1 = offs[gw + 1];
    float acc = 0.f;
    for (int i = s0; i < s1; ++i) {
        int nbr = nbr_s[i];
        float w = ew_s[i];
        acc += w * y[(size_t)nbr * 64 + lane];
    }
    float cnt = (float)(s1 - s0);
    agg[(size_t)gw * 64 + lane] = acc / fmaxf(cnt, 1.0f);
}

// ---------------------------------------------------------------------------
extern "C" void kernel_launch(void* const* d_in, const int* in_sizes, int n_in,
                              void* d_out, int out_size, void* d_ws, size_t ws_size,
                              hipStream_t stream) {
    const float* x    = (const float*)d_in[0];
    const int*   edges= (const int*)d_in[1];
    const float* ew   = (const float*)d_in[2];
    const float* pbn1 = (const float*)d_in[3];
    const float* pw1  = (const float*)d_in[4];
    const float* pc1  = (const float*)d_in[5];
    const float* pbn2 = (const float*)d_in[6];
    const float* pw2  = (const float*)d_in[7];
    const float* pc2  = (const float*)d_in[8];
    const float* ubn1 = (const float*)d_in[9];
    const float* uw1  = (const float*)d_in[10];
    const float* uc1  = (const float*)d_in[11];
    const float* ubn2 = (const float*)d_in[12];
    const float* uw2  = (const float*)d_in[13];
    const float* uc2  = (const float*)d_in[14];
    float* out = (float*)d_out;

    const int N = in_sizes[0] / 64;
    const int E = in_sizes[2];
    const int* node_idx = edges;
    const int* nbr_idx  = edges + E;

    // workspace carve-up (256B aligned); total ~40 MB
    char* p = (char*)d_ws;
    auto alloc = [&](size_t bytes) {
        char* q = p;
        p += (bytes + 255) & ~(size_t)255;
        return q;
    };
    float* h1    = (float*)alloc((size_t)N * 64 * 4);  // agg buffer
    float* W1t   = (float*)alloc(64 * 64 * 4);
    float* c1p   = (float*)alloc(64 * 4);
    float* W2t   = (float*)alloc(64 * 64 * 4);
    float* c2p   = (float*)alloc(64 * 4);
    float* U1t   = (float*)alloc(128 * 64 * 4);
    float* uc1p  = (float*)alloc(64 * 4);
    float* U2t   = (float*)alloc(64 * 64 * 4);
    float* uc2p  = (float*)alloc(64 * 4);
    float* ew_s  = (float*)alloc((size_t)E * 4);
    int*   nbr_s = (int*)alloc((size_t)E * 4);
    int*   deg   = (int*)alloc((size_t)N * 4);
    int*   offs  = (int*)alloc((size_t)(N + 1) * 4);
    int*   cur   = (int*)alloc((size_t)N * 4);

    float* yb = out;  // d_out doubles as y (consumed by agg before final write)

    hipMemsetAsync(deg, 0, (size_t)N * 4, stream);
    prep_kernel<<<1, 128, 0, stream>>>(pbn1, pw1, pc1, pbn2, pw2, pc2,
                                       ubn1, uw1, uc1, ubn2, uw2, uc2,
                                       W1t, c1p, W2t, c2p, U1t, uc1p, U2t, uc2p);
    hist_kernel<<<(E + 255) / 256, 256, 0, stream>>>(node_idx, deg, E);
    scan_kernel<<<1, 1024, 0, stream>>>(deg, offs, N);
    copy_kernel<<<(N + 255) / 256, 256, 0, stream>>>(offs, cur, N);
    scatter_kernel<<<(E + 255) / 256, 256, 0, stream>>>(node_idx, nbr_idx, ew, cur,
                                                        nbr_s, ew_s, E);

    const int fblocks = (N + 63) / 64;
    // node-level fused FFN: y = FFN2(FFN1(x))  (per node, not per edge)
    ffn2_fused<64><<<fblocks, 256, 0, stream>>>(x, nullptr, W1t, c1p, W2t, c2p, yb, N);
    // segment mean of y[nbr]*ew over node_idx
    agg_kernel<<<(N + 3) / 4, 256, 0, stream>>>(yb, offs, nbr_s, ew_s, h1, N);
    // update fused FFN on concat(x, agg) -> out
    ffn2_fused<128><<<fblocks, 256, 0, stream>>>(x, h1, U1t, uc1p, U2t, uc2p, out, N);
}

// Round 3
// 374.226 us; speedup vs baseline: 2.2713x; 2.2368x over previous
//
#include <hip/hip_runtime.h>
#include <hip/hip_bf16.h>

#define BN_EPS 1e-3f

typedef __attribute__((ext_vector_type(8))) short short8;
typedef __attribute__((ext_vector_type(4))) float f32x4;

__device__ __forceinline__ float gelu_exact(float v) {
    return 0.5f * v * (1.0f + erff(v * 0.70710678118654752440f));
}
__device__ __forceinline__ short f2b(float f) {
    __hip_bfloat16 h = __float2bfloat16(f);  // RNE
    return *reinterpret_cast<short*>(&h);
}
__device__ __forceinline__ float b2f(unsigned short u) {
    union { unsigned i; float f; } c;
    c.i = ((unsigned)u) << 16;
    return c.f;
}

// ---------------------------------------------------------------------------
// prep: fold inference BN into weights, convert to bf16, and pre-swizzle into
// MFMA B-fragment order for v_mfma_f32_16x16x32_bf16:
//   frag idx f = t*KC + h (t = 16-col tile, h = 32-wide K chunk)
//   Wswz[(f*64 + lane)*8 + j] = bf16( s[k] * W[k*64 + col] )
//     k = h*32 + (lane>>4)*8 + j,  col = t*16 + (lane&15)
// bias cp[j] = c[j] + sum_k t[k]*W[k*64+j]
// ---------------------------------------------------------------------------
template <int K>
__device__ void foldK_swz(const float* __restrict__ bn, const float* __restrict__ W,
                          const float* __restrict__ c, short* __restrict__ Wswz,
                          float* __restrict__ cp, float* sh_s, float* sh_t) {
    const int tid = threadIdx.x;  // blockDim 256
    if (tid < K) {
        float g = bn[tid], b = bn[K + tid], m = bn[2 * K + tid], v = bn[3 * K + tid];
        float s = g * rsqrtf(v + BN_EPS);
        sh_s[tid] = s;
        sh_t[tid] = b - m * s;
    }
    __syncthreads();
    constexpr int KC = K / 32;
    for (int idx = tid; idx < 4 * KC * 64 * 8; idx += 256) {
        int j = idx & 7, lane = (idx >> 3) & 63, f = idx >> 9;
        int h = f % KC, t = f / KC;
        int k = h * 32 + (lane >> 4) * 8 + j;
        int col = t * 16 + (lane & 15);
        Wswz[idx] = f2b(sh_s[k] * W[k * 64 + col]);
    }
    if (tid < 64) {
        float acc = c[tid];
        for (int k = 0; k < K; ++k) acc += sh_t[k] * W[k * 64 + tid];
        cp[tid] = acc;
    }
    __syncthreads();
}

__global__ void prep_kernel(
    const float* pbn1, const float* pw1, const float* pc1,
    const float* pbn2, const float* pw2, const float* pc2,
    const float* ubn1, const float* uw1, const float* uc1,
    const float* ubn2, const float* uw2, const float* uc2,
    short* W1s, float* c1p, short* W2s, float* c2p,
    short* U1s, float* uc1p, short* U2s, float* uc2p) {
    __shared__ float sh_s[128], sh_t[128];
    foldK_swz<64>(pbn1, pw1, pc1, W1s, c1p, sh_s, sh_t);
    foldK_swz<64>(pbn2, pw2, pc2, W2s, c2p, sh_s, sh_t);
    foldK_swz<128>(ubn1, uw1, uc1, U1s, uc1p, sh_s, sh_t);
    foldK_swz<64>(ubn2, uw2, uc2, U2s, uc2p, sh_s, sh_t);
}

// ---------------------------------------------------------------------------
// Fused 2-layer FFN on the matrix pipe.
//   out = gelu(gelu(concat(X, A1)[row,:] @ W1 + c1) @ W2 + c2)
// Block = 256 thr = 4 waves = 64 rows; wave = one 16-row MFMA tile over all
// 64 output cols (4 col-tiles x K/32 MFMAs). X is f32 (converted inline),
// A1 (when K1==128) is bf16. Layer1->layer2 handoff via wave-private LDS
// tile (no barriers needed).
// ---------------------------------------------------------------------------
template <int K1, bool OUT_BF16>
__global__ void __launch_bounds__(256) ffn2_mfma(
    const float* __restrict__ X, const short* __restrict__ A1,
    const short* __restrict__ W1s, const float* __restrict__ c1,
    const short* __restrict__ W2s, const float* __restrict__ c2,
    void* __restrict__ outv, int N) {
    __shared__ short Hs[4][16][72];  // per-wave 16x64 h tile (+8 pad)
    const int tid = threadIdx.x;
    const int lane = tid & 63;
    const int wv = tid >> 6;
    const int lm = lane & 15, lh = lane >> 4;
    const int r0 = blockIdx.x * 64 + wv * 16;
    if (r0 >= N) return;
    const int rowA = min(r0 + lm, N - 1);
    constexpr int KC1 = K1 / 32;

    // A fragments: k = h*32 + lh*8 + j
    short8 a[KC1];
    {
        const float* xp = X + (size_t)rowA * 64 + lh * 8;
#pragma unroll
        for (int h = 0; h < 2; ++h) {
            float4 u0 = *reinterpret_cast<const float4*>(xp + h * 32);
            float4 u1 = *reinterpret_cast<const float4*>(xp + h * 32 + 4);
            short8 r;
            r[0] = f2b(u0.x); r[1] = f2b(u0.y); r[2] = f2b(u0.z); r[3] = f2b(u0.w);
            r[4] = f2b(u1.x); r[5] = f2b(u1.y); r[6] = f2b(u1.z); r[7] = f2b(u1.w);
            a[h] = r;
        }
        if (K1 == 128) {
#pragma unroll
            for (int h = 0; h < 2; ++h)
                a[2 + h] = *reinterpret_cast<const short8*>(
                    A1 + (size_t)rowA * 64 + h * 32 + lh * 8);
        }
    }

    // layer 1 + gelu -> LDS (bf16)
#pragma unroll
    for (int t = 0; t < 4; ++t) {
        float cb = c1[t * 16 + lm];
        f32x4 acc = {cb, cb, cb, cb};
#pragma unroll
        for (int h = 0; h < KC1; ++h) {
            short8 b = *reinterpret_cast<const short8*>(
                W1s + ((size_t)(t * KC1 + h) * 64 + lane) * 8);
            acc = __builtin_amdgcn_mfma_f32_16x16x32_bf16(a[h], b, acc, 0, 0, 0);
        }
#pragma unroll
        for (int q = 0; q < 4; ++q)
            Hs[wv][4 * lh + q][t * 16 + lm] = f2b(gelu_exact(acc[q]));
    }

    // layer 2 A-frags from LDS
    short8 a2[2];
#pragma unroll
    for (int h = 0; h < 2; ++h)
        a2[h] = *reinterpret_cast<const short8*>(&Hs[wv][lm][h * 32 + lh * 8]);

#pragma unroll
    for (int t = 0; t < 4; ++t) {
        float cb = c2[t * 16 + lm];
        f32x4 acc = {cb, cb, cb, cb};
#pragma unroll
        for (int h = 0; h < 2; ++h) {
            short8 b = *reinterpret_cast<const short8*>(
                W2s + ((size_t)(t * 2 + h) * 64 + lane) * 8);
            acc = __builtin_amdgcn_mfma_f32_16x16x32_bf16(a2[h], b, acc, 0, 0, 0);
        }
#pragma unroll
        for (int q = 0; q < 4; ++q) {
            int row = r0 + 4 * lh + q;
            if (row < N) {
                float o = gelu_exact(acc[q]);
                if (OUT_BF16)
                    ((short*)outv)[(size_t)row * 64 + t * 16 + lm] = f2b(o);
                else
                    ((float*)outv)[(size_t)row * 64 + t * 16 + lm] = o;
            }
        }
    }
}

// ---------------------------------------------------------------------------
// CSR build: histogram -> hierarchical scan (chunk sums, 1-wave chunk scan,
// per-chunk scan+write of offs AND cur) -> scatter of packed (nbr, ew).
// ---------------------------------------------------------------------------
__global__ void hist_kernel(const int* __restrict__ node_idx, int* __restrict__ deg, int E) {
    int e = blockIdx.x * 256 + threadIdx.x;
    if (e < E) atomicAdd(&deg[node_idx[e]], 1);
}

__global__ void chunksum_kernel(const int* __restrict__ deg, int* __restrict__ csum, int N) {
    __shared__ int ws[4];
    int tid = threadIdx.x, lane = tid & 63, wv = tid >> 6;
    int base = blockIdx.x * 2048 + tid * 8;
    int s = 0;
#pragma unroll
    for (int j = 0; j < 8; ++j) {
        int i = base + j;
        if (i < N) s += deg[i];
    }
#pragma unroll
    for (int d = 1; d < 64; d <<= 1) s += __shfl_down(s, (unsigned)d, 64);
    if (lane == 0) ws[wv] = s;
    __syncthreads();
    if (tid == 0) csum[blockIdx.x] = ws[0] + ws[1] + ws[2] + ws[3];
}

__global__ void scan_chunks(int* csum, int* offs, int nc, int N) {
    int lane = threadIdx.x;  // blockDim 64
    int carry = 0;
    for (int base = 0; base < nc; base += 64) {
        int i = base + lane;
        int v = (i < nc) ? csum[i] : 0, orig = v;
#pragma unroll
        for (int d = 1; d < 64; d <<= 1) {
            int n = __shfl_up(v, (unsigned)d, 64);
            if (lane >= d) v += n;
        }
        if (i < nc) csum[i] = carry + v - orig;  // exclusive chunk offset
        carry += __shfl(v, 63, 64);
    }
    if (lane == 0) offs[N] = carry;
}

__global__ void scan_write(const int* __restrict__ deg, const int* __restrict__ csum,
                           int* __restrict__ offs, int* __restrict__ cur, int N) {
    __shared__ int ws[4];
    int tid = threadIdx.x, lane = tid & 63, wv = tid >> 6;
    int base = blockIdx.x * 2048 + tid * 8;
    int v[8], p = 0;
#pragma unroll
    for (int j = 0; j < 8; ++j) {
        int i = base + j;
        v[j] = (i < N) ? deg[i] : 0;
        p += v[j];
    }
    int inc = p;
#pragma unroll
    for (int d = 1; d < 64; d <<= 1) {
        int n = __shfl_up(inc, (unsigned)d, 64);
        if (lane >= d) inc += n;
    }
    if (lane == 63) ws[wv] = inc;
    __syncthreads();
    int run = csum[blockIdx.x] + (inc - p);
    for (int w = 0; w < wv; ++w) run += ws[w];
#pragma unroll
    for (int j = 0; j < 8; ++j) {
        int i = base + j;
        if (i < N) {
            offs[i] = run;
            cur[i] = run;
        }
        run += v[j];
    }
}

__global__ void scatter_kernel(const int* __restrict__ node_idx, const int* __restrict__ nbr_idx,
                               const float* __restrict__ ew, int* __restrict__ cur,
                               int2* __restrict__ es, int E) {
    int e = blockIdx.x * 256 + threadIdx.x;
    if (e < E) {
        int p = atomicAdd(&cur[node_idx[e]], 1);
        es[p] = make_int2(nbr_idx[e], __float_as_int(ew[e]));
    }
}

// ---------------------------------------------------------------------------
// aggregation: wave per node, lane = feature. y rows are bf16 (128B/row),
// edge payload is one 8B broadcast load; 2-edge unroll for latency.
// ---------------------------------------------------------------------------
__global__ void agg_kernel(const unsigned short* __restrict__ yb, const int* __restrict__ offs,
                           const int2* __restrict__ es, short* __restrict__ aggb, int N) {
    int node = (blockIdx.x * 256 + threadIdx.x) >> 6;
    int lane = threadIdx.x & 63;
    if (node >= N) return;
    int s0 = offs[node], s1 = offs[node + 1];
    float acc = 0.f;
    int i = s0;
    for (; i + 1 < s1; i += 2) {
        int2 e0 = es[i], e1 = es[i + 1];
        float y0 = b2f(yb[(size_t)e0.x * 64 + lane]);
        float y1 = b2f(yb[(size_t)e1.x * 64 + lane]);
        acc += __int_as_float(e0.y) * y0;
        acc += __int_as_float(e1.y) * y1;
    }
    if (i < s1) {
        int2 e = es[i];
        acc += __int_as_float(e.y) * b2f(yb[(size_t)e.x * 64 + lane]);
    }
    aggb[(size_t)node * 64 + lane] = f2b(acc / fmaxf((float)(s1 - s0), 1.f));
}

// ---------------------------------------------------------------------------
extern "C" void kernel_launch(void* const* d_in, const int* in_sizes, int n_in,
                              void* d_out, int out_size, void* d_ws, size_t ws_size,
                              hipStream_t stream) {
    const float* x    = (const float*)d_in[0];
    const int*   edges= (const int*)d_in[1];
    const float* ew   = (const float*)d_in[2];
    const float* pbn1 = (const float*)d_in[3];
    const float* pw1  = (const float*)d_in[4];
    const float* pc1  = (const float*)d_in[5];
    const float* pbn2 = (const float*)d_in[6];
    const float* pw2  = (const float*)d_in[7];
    const float* pc2  = (const float*)d_in[8];
    const float* ubn1 = (const float*)d_in[9];
    const float* uw1  = (const float*)d_in[10];
    const float* uc1  = (const float*)d_in[11];
    const float* ubn2 = (const float*)d_in[12];
    const float* uw2  = (const float*)d_in[13];
    const float* uc2  = (const float*)d_in[14];
    float* out = (float*)d_out;

    const int N = in_sizes[0] / 64;
    const int E = in_sizes[2];
    const int* node_idx = edges;
    const int* nbr_idx  = edges + E;
    const int nchunks = (N + 2047) / 2048;

    // workspace carve-up (256B aligned); ~40 MB total
    char* p = (char*)d_ws;
    auto alloc = [&](size_t bytes) {
        char* q = p;
        p += (bytes + 255) & ~(size_t)255;
        return q;
    };
    short* yb    = (short*)alloc((size_t)N * 64 * 2);   // y (bf16)
    short* aggb  = (short*)alloc((size_t)N * 64 * 2);   // agg (bf16)
    int2*  es    = (int2*)alloc((size_t)E * 8);         // packed (nbr, ew)
    int*   deg   = (int*)alloc((size_t)N * 4);
    int*   offs  = (int*)alloc((size_t)(N + 1) * 4);
    int*   cur   = (int*)alloc((size_t)N * 4);
    int*   csum  = (int*)alloc((size_t)nchunks * 4);
    short* W1s   = (short*)alloc(4096 * 2);
    short* W2s   = (short*)alloc(4096 * 2);
    short* U1s   = (short*)alloc(8192 * 2);
    short* U2s   = (short*)alloc(4096 * 2);
    float* c1p   = (float*)alloc(64 * 4);
    float* c2p   = (float*)alloc(64 * 4);
    float* uc1p  = (float*)alloc(64 * 4);
    float* uc2p  = (float*)alloc(64 * 4);

    hipMemsetAsync(deg, 0, (size_t)N * 4, stream);
    prep_kernel<<<1, 256, 0, stream>>>(pbn1, pw1, pc1, pbn2, pw2, pc2,
                                       ubn1, uw1, uc1, ubn2, uw2, uc2,
                                       W1s, c1p, W2s, c2p, U1s, uc1p, U2s, uc2p);
    hist_kernel<<<(E + 255) / 256, 256, 0, stream>>>(node_idx, deg, E);
    chunksum_kernel<<<nchunks, 256, 0, stream>>>(deg, csum, N);
    scan_chunks<<<1, 64, 0, stream>>>(csum, offs, nchunks, N);
    scan_write<<<nchunks, 256, 0, stream>>>(deg, csum, offs, cur, N);
    scatter_kernel<<<(E + 255) / 256, 256, 0, stream>>>(node_idx, nbr_idx, ew, cur, es, E);

    const int fblocks = (N + 63) / 64;
    // node-level fused FFN: y = FFN2(FFN1(x))  (bf16 out for the gather)
    ffn2_mfma<64, true><<<fblocks, 256, 0, stream>>>(x, nullptr, W1s, c1p, W2s, c2p, yb, N);
    // segment mean of y[nbr]*ew over node_idx
    agg_kernel<<<(N * 64 + 255) / 256, 256, 0, stream>>>((const unsigned short*)yb, offs, es, aggb, N);
    // update fused FFN on concat(x, agg) -> out (f32)
    ffn2_mfma<128, false><<<fblocks, 256, 0, stream>>>(x, aggb, U1s, uc1p, U2s, uc2p, out, N);
}

// Round 4
// 304.651 us; speedup vs baseline: 2.7901x; 1.2284x over previous
//
#include <hip/hip_runtime.h>
#include <hip/hip_bf16.h>

#define BN_EPS 1e-3f

typedef __attribute__((ext_vector_type(8))) short short8;
typedef __attribute__((ext_vector_type(8))) unsigned short bv8;
typedef __attribute__((ext_vector_type(4))) float f32x4;

__device__ __forceinline__ float gelu_exact(float v) {
    return 0.5f * v * (1.0f + erff(v * 0.70710678118654752440f));
}
__device__ __forceinline__ short f2b(float f) {
    __hip_bfloat16 h = __float2bfloat16(f);  // RNE
    return *reinterpret_cast<short*>(&h);
}
__device__ __forceinline__ float b2f(unsigned short u) {
    union { unsigned i; float f; } c;
    c.i = ((unsigned)u) << 16;
    return c.f;
}

// ---------------------------------------------------------------------------
// prep: fold inference BN into weights, convert to bf16, and pre-swizzle into
// MFMA B-fragment order for v_mfma_f32_16x16x32_bf16:
//   frag idx f = t*KC + h (t = 16-col tile, h = 32-wide K chunk)
//   Wswz[(f*64 + lane)*8 + j] = bf16( s[k] * W[k*64 + col] )
//     k = h*32 + (lane>>4)*8 + j,  col = t*16 + (lane&15)
// bias cp[j] = c[j] + sum_k t[k]*W[k*64+j]
// ---------------------------------------------------------------------------
template <int K>
__device__ void foldK_swz(const float* __restrict__ bn, const float* __restrict__ W,
                          const float* __restrict__ c, short* __restrict__ Wswz,
                          float* __restrict__ cp, float* sh_s, float* sh_t) {
    const int tid = threadIdx.x;  // blockDim 256
    if (tid < K) {
        float g = bn[tid], b = bn[K + tid], m = bn[2 * K + tid], v = bn[3 * K + tid];
        float s = g * rsqrtf(v + BN_EPS);
        sh_s[tid] = s;
        sh_t[tid] = b - m * s;
    }
    __syncthreads();
    constexpr int KC = K / 32;
    for (int idx = tid; idx < 4 * KC * 64 * 8; idx += 256) {
        int j = idx & 7, lane = (idx >> 3) & 63, f = idx >> 9;
        int h = f % KC, t = f / KC;
        int k = h * 32 + (lane >> 4) * 8 + j;
        int col = t * 16 + (lane & 15);
        Wswz[idx] = f2b(sh_s[k] * W[k * 64 + col]);
    }
    if (tid < 64) {
        float acc = c[tid];
        for (int k = 0; k < K; ++k) acc += sh_t[k] * W[k * 64 + tid];
        cp[tid] = acc;
    }
    __syncthreads();
}

__global__ void prep_kernel(
    const float* pbn1, const float* pw1, const float* pc1,
    const float* pbn2, const float* pw2, const float* pc2,
    const float* ubn1, const float* uw1, const float* uc1,
    const float* ubn2, const float* uw2, const float* uc2,
    short* W1s, float* c1p, short* W2s, float* c2p,
    short* U1s, float* uc1p, short* U2s, float* uc2p) {
    __shared__ float sh_s[128], sh_t[128];
    foldK_swz<64>(pbn1, pw1, pc1, W1s, c1p, sh_s, sh_t);
    foldK_swz<64>(pbn2, pw2, pc2, W2s, c2p, sh_s, sh_t);
    foldK_swz<128>(ubn1, uw1, uc1, U1s, uc1p, sh_s, sh_t);
    foldK_swz<64>(ubn2, uw2, uc2, U2s, uc2p, sh_s, sh_t);
}

// ---------------------------------------------------------------------------
// Fused 2-layer FFN on the matrix pipe.
//   out = gelu(gelu(concat(X, A1)[row,:] @ W1 + c1) @ W2 + c2)
// Block = 256 thr = 4 waves = 64 rows; wave = one 16-row MFMA tile over all
// 64 output cols (4 col-tiles x K/32 MFMAs). X is f32 (converted inline),
// A1 (when K1==128) is bf16. Layer1->layer2 handoff via wave-private LDS
// tile (no barriers needed).
// ---------------------------------------------------------------------------
template <int K1, bool OUT_BF16>
__global__ void __launch_bounds__(256) ffn2_mfma(
    const float* __restrict__ X, const short* __restrict__ A1,
    const short* __restrict__ W1s, const float* __restrict__ c1,
    const short* __restrict__ W2s, const float* __restrict__ c2,
    void* __restrict__ outv, int N) {
    __shared__ short Hs[4][16][72];  // per-wave 16x64 h tile (+8 pad)
    const int tid = threadIdx.x;
    const int lane = tid & 63;
    const int wv = tid >> 6;
    const int lm = lane & 15, lh = lane >> 4;
    const int r0 = blockIdx.x * 64 + wv * 16;
    if (r0 >= N) return;
    const int rowA = min(r0 + lm, N - 1);
    constexpr int KC1 = K1 / 32;

    // A fragments: k = h*32 + lh*8 + j
    short8 a[KC1];
    {
        const float* xp = X + (size_t)rowA * 64 + lh * 8;
#pragma unroll
        for (int h = 0; h < 2; ++h) {
            float4 u0 = *reinterpret_cast<const float4*>(xp + h * 32);
            float4 u1 = *reinterpret_cast<const float4*>(xp + h * 32 + 4);
            short8 r;
            r[0] = f2b(u0.x); r[1] = f2b(u0.y); r[2] = f2b(u0.z); r[3] = f2b(u0.w);
            r[4] = f2b(u1.x); r[5] = f2b(u1.y); r[6] = f2b(u1.z); r[7] = f2b(u1.w);
            a[h] = r;
        }
        if (K1 == 128) {
#pragma unroll
            for (int h = 0; h < 2; ++h)
                a[2 + h] = *reinterpret_cast<const short8*>(
                    A1 + (size_t)rowA * 64 + h * 32 + lh * 8);
        }
    }

    // layer 1 + gelu -> LDS (bf16)
#pragma unroll
    for (int t = 0; t < 4; ++t) {
        float cb = c1[t * 16 + lm];
        f32x4 acc = {cb, cb, cb, cb};
#pragma unroll
        for (int h = 0; h < KC1; ++h) {
            short8 b = *reinterpret_cast<const short8*>(
                W1s + ((size_t)(t * KC1 + h) * 64 + lane) * 8);
            acc = __builtin_amdgcn_mfma_f32_16x16x32_bf16(a[h], b, acc, 0, 0, 0);
        }
#pragma unroll
        for (int q = 0; q < 4; ++q)
            Hs[wv][4 * lh + q][t * 16 + lm] = f2b(gelu_exact(acc[q]));
    }

    // layer 2 A-frags from LDS
    short8 a2[2];
#pragma unroll
    for (int h = 0; h < 2; ++h)
        a2[h] = *reinterpret_cast<const short8*>(&Hs[wv][lm][h * 32 + lh * 8]);

#pragma unroll
    for (int t = 0; t < 4; ++t) {
        float cb = c2[t * 16 + lm];
        f32x4 acc = {cb, cb, cb, cb};
#pragma unroll
        for (int h = 0; h < 2; ++h) {
            short8 b = *reinterpret_cast<const short8*>(
                W2s + ((size_t)(t * 2 + h) * 64 + lane) * 8);
            acc = __builtin_amdgcn_mfma_f32_16x16x32_bf16(a2[h], b, acc, 0, 0, 0);
        }
#pragma unroll
        for (int q = 0; q < 4; ++q) {
            int row = r0 + 4 * lh + q;
            if (row < N) {
                float o = gelu_exact(acc[q]);
                if (OUT_BF16)
                    ((short*)outv)[(size_t)row * 64 + t * 16 + lm] = f2b(o);
                else
                    ((float*)outv)[(size_t)row * 64 + t * 16 + lm] = o;
            }
        }
    }
}

// ---------------------------------------------------------------------------
// CSR build: histogram -> hierarchical scan -> scatter of packed (nbr, ew).
// hist/scatter are 4-way unrolled: 4 independent atomic (+write) chains in
// flight per thread (they are latency-bound, not BW-bound).
// ---------------------------------------------------------------------------
__global__ void hist_kernel(const int* __restrict__ node_idx, int* __restrict__ deg,
                            int E, int T) {
    int t = blockIdx.x * 256 + threadIdx.x;
    int n[4];
    bool v[4];
#pragma unroll
    for (int j = 0; j < 4; ++j) {
        int e = t + j * T;
        v[j] = e < E;
        n[j] = v[j] ? node_idx[e] : 0;
    }
#pragma unroll
    for (int j = 0; j < 4; ++j)
        if (v[j]) atomicAdd(&deg[n[j]], 1);
}

__global__ void chunksum_kernel(const int* __restrict__ deg, int* __restrict__ csum, int N) {
    __shared__ int ws[4];
    int tid = threadIdx.x, lane = tid & 63, wv = tid >> 6;
    int base = blockIdx.x * 2048 + tid * 8;
    int s = 0;
#pragma unroll
    for (int j = 0; j < 8; ++j) {
        int i = base + j;
        if (i < N) s += deg[i];
    }
#pragma unroll
    for (int d = 1; d < 64; d <<= 1) s += __shfl_down(s, (unsigned)d, 64);
    if (lane == 0) ws[wv] = s;
    __syncthreads();
    if (tid == 0) csum[blockIdx.x] = ws[0] + ws[1] + ws[2] + ws[3];
}

__global__ void scan_chunks(int* csum, int* offs, int nc, int N) {
    int lane = threadIdx.x;  // blockDim 64
    int carry = 0;
    for (int base = 0; base < nc; base += 64) {
        int i = base + lane;
        int v = (i < nc) ? csum[i] : 0, orig = v;
#pragma unroll
        for (int d = 1; d < 64; d <<= 1) {
            int n = __shfl_up(v, (unsigned)d, 64);
            if (lane >= d) v += n;
        }
        if (i < nc) csum[i] = carry + v - orig;  // exclusive chunk offset
        carry += __shfl(v, 63, 64);
    }
    if (lane == 0) offs[N] = carry;
}

__global__ void scan_write(const int* __restrict__ deg, const int* __restrict__ csum,
                           int* __restrict__ offs, int* __restrict__ cur, int N) {
    __shared__ int ws[4];
    int tid = threadIdx.x, lane = tid & 63, wv = tid >> 6;
    int base = blockIdx.x * 2048 + tid * 8;
    int v[8], p = 0;
#pragma unroll
    for (int j = 0; j < 8; ++j) {
        int i = base + j;
        v[j] = (i < N) ? deg[i] : 0;
        p += v[j];
    }
    int inc = p;
#pragma unroll
    for (int d = 1; d < 64; d <<= 1) {
        int n = __shfl_up(inc, (unsigned)d, 64);
        if (lane >= d) inc += n;
    }
    if (lane == 63) ws[wv] = inc;
    __syncthreads();
    int run = csum[blockIdx.x] + (inc - p);
    for (int w = 0; w < wv; ++w) run += ws[w];
#pragma unroll
    for (int j = 0; j < 8; ++j) {
        int i = base + j;
        if (i < N) {
            offs[i] = run;
            cur[i] = run;
        }
        run += v[j];
    }
}

__global__ void scatter_kernel(const int* __restrict__ node_idx, const int* __restrict__ nbr_idx,
                               const float* __restrict__ ew, int* __restrict__ cur,
                               int2* __restrict__ es, int E, int T) {
    int t = blockIdx.x * 256 + threadIdx.x;
    int n[4], p[4];
    int2 pay[4];
    bool v[4];
#pragma unroll
    for (int j = 0; j < 4; ++j) {
        int e = t + j * T;
        v[j] = e < E;
        if (v[j]) {
            n[j] = node_idx[e];
            pay[j] = make_int2(nbr_idx[e], __float_as_int(ew[e]));
        }
    }
#pragma unroll
    for (int j = 0; j < 4; ++j)
        if (v[j]) p[j] = atomicAdd(&cur[n[j]], 1);
#pragma unroll
    for (int j = 0; j < 4; ++j)
        if (v[j]) es[p[j]] = pay[j];
}

// ---------------------------------------------------------------------------
// aggregation: wave per node, 8 groups of 8 lanes; group g handles edges
// s0+g, s0+g+8, ... Each lane loads 16B (8 bf16 feats) -> one wave
// instruction has 8 random 128B gathers in flight. Cross-group combine via
// shfl_xor(8,16,32); lanes 0-7 write the 128B bf16 row.
// ---------------------------------------------------------------------------
__global__ void agg_kernel(const unsigned short* __restrict__ yb, const int* __restrict__ offs,
                           const int2* __restrict__ es, short* __restrict__ aggb, int N) {
    int node = (blockIdx.x * 256 + threadIdx.x) >> 6;
    int lane = threadIdx.x & 63;
    if (node >= N) return;
    const int g = lane >> 3, lg = lane & 7;
    int s0 = offs[node], s1 = offs[node + 1];
    float acc[8] = {0.f, 0.f, 0.f, 0.f, 0.f, 0.f, 0.f, 0.f};
    for (int i = s0 + g; i < s1; i += 8) {
        int2 e = es[i];
        bv8 yv = *reinterpret_cast<const bv8*>(yb + (size_t)e.x * 64 + lg * 8);
        float w = __int_as_float(e.y);
#pragma unroll
        for (int j = 0; j < 8; ++j) acc[j] += w * b2f(yv[j]);
    }
#pragma unroll
    for (int m = 8; m <= 32; m <<= 1) {
#pragma unroll
        for (int j = 0; j < 8; ++j) acc[j] += __shfl_xor(acc[j], m, 64);
    }
    if (lane < 8) {
        float rcnt = 1.f / fmaxf((float)(s1 - s0), 1.f);
        short8 o;
#pragma unroll
        for (int j = 0; j < 8; ++j) o[j] = f2b(acc[j] * rcnt);
        *reinterpret_cast<short8*>(aggb + (size_t)node * 64 + lg * 8) = o;
    }
}

// ---------------------------------------------------------------------------
extern "C" void kernel_launch(void* const* d_in, const int* in_sizes, int n_in,
                              void* d_out, int out_size, void* d_ws, size_t ws_size,
                              hipStream_t stream) {
    const float* x    = (const float*)d_in[0];
    const int*   edges= (const int*)d_in[1];
    const float* ew   = (const float*)d_in[2];
    const float* pbn1 = (const float*)d_in[3];
    const float* pw1  = (const float*)d_in[4];
    const float* pc1  = (const float*)d_in[5];
    const float* pbn2 = (const float*)d_in[6];
    const float* pw2  = (const float*)d_in[7];
    const float* pc2  = (const float*)d_in[8];
    const float* ubn1 = (const float*)d_in[9];
    const float* uw1  = (const float*)d_in[10];
    const float* uc1  = (const float*)d_in[11];
    const float* ubn2 = (const float*)d_in[12];
    const float* uw2  = (const float*)d_in[13];
    const float* uc2  = (const float*)d_in[14];
    float* out = (float*)d_out;

    const int N = in_sizes[0] / 64;
    const int E = in_sizes[2];
    const int* node_idx = edges;
    const int* nbr_idx  = edges + E;
    const int nchunks = (N + 2047) / 2048;

    // workspace carve-up (256B aligned); ~40 MB total
    char* p = (char*)d_ws;
    auto alloc = [&](size_t bytes) {
        char* q = p;
        p += (bytes + 255) & ~(size_t)255;
        return q;
    };
    short* yb    = (short*)alloc((size_t)N * 64 * 2);   // y (bf16)
    short* aggb  = (short*)alloc((size_t)N * 64 * 2);   // agg (bf16)
    int2*  es    = (int2*)alloc((size_t)E * 8);         // packed (nbr, ew)
    int*   deg   = (int*)alloc((size_t)N * 4);
    int*   offs  = (int*)alloc((size_t)(N + 1) * 4);
    int*   cur   = (int*)alloc((size_t)N * 4);
    int*   csum  = (int*)alloc((size_t)nchunks * 4);
    short* W1s   = (short*)alloc(4096 * 2);
    short* W2s   = (short*)alloc(4096 * 2);
    short* U1s   = (short*)alloc(8192 * 2);
    short* U2s   = (short*)alloc(4096 * 2);
    float* c1p   = (float*)alloc(64 * 4);
    float* c2p   = (float*)alloc(64 * 4);
    float* uc1p  = (float*)alloc(64 * 4);
    float* uc2p  = (float*)alloc(64 * 4);

    hipMemsetAsync(deg, 0, (size_t)N * 4, stream);
    prep_kernel<<<1, 256, 0, stream>>>(pbn1, pw1, pc1, pbn2, pw2, pc2,
                                       ubn1, uw1, uc1, ubn2, uw2, uc2,
                                       W1s, c1p, W2s, c2p, U1s, uc1p, U2s, uc2p);
    {
        const int nb = (E + 4 * 256 - 1) / (4 * 256);
        hist_kernel<<<nb, 256, 0, stream>>>(node_idx, deg, E, nb * 256);
    }
    chunksum_kernel<<<nchunks, 256, 0, stream>>>(deg, csum, N);
    scan_chunks<<<1, 64, 0, stream>>>(csum, offs, nchunks, N);
    scan_write<<<nchunks, 256, 0, stream>>>(deg, csum, offs, cur, N);
    {
        const int nb = (E + 4 * 256 - 1) / (4 * 256);
        scatter_kernel<<<nb, 256, 0, stream>>>(node_idx, nbr_idx, ew, cur, es, E, nb * 256);
    }

    const int fblocks = (N + 63) / 64;
    // node-level fused FFN: y = FFN2(FFN1(x))  (bf16 out for the gather)
    ffn2_mfma<64, true><<<fblocks, 256, 0, stream>>>(x, nullptr, W1s, c1p, W2s, c2p, yb, N);
    // segment mean of y[nbr]*ew over node_idx
    agg_kernel<<<(N * 64 + 255) / 256, 256, 0, stream>>>((const unsigned short*)yb, offs, es, aggb, N);
    // update fused FFN on concat(x, agg) -> out (f32)
    ffn2_mfma<128, false><<<fblocks, 256, 0, stream>>>(x, aggb, U1s, uc1p, U2s, uc2p, out, N);
}